// Round 1
// baseline (5414.732 us; speedup 1.0000x reference)
//
#include <hip/hip_runtime.h>
#include <math.h>

#define DFEAT 128
#define EPS_C 0.01f

// ---------------- edge preprocessing ----------------

__global__ __launch_bounds__(256) void edge_prep_kernel(
    const int* __restrict__ rows, const float* __restrict__ wval,
    const float* __restrict__ kappa, const float* __restrict__ alpha_p,
    const float* __restrict__ center_p, float* __restrict__ w_prime,
    float* __restrict__ deg, int* __restrict__ count, int E)
{
    int e = blockIdx.x * 256 + threadIdx.x;
    if (e >= E) return;
    float a = alpha_p[0];
    float c = center_p[0];
    float sp = (a > 20.f) ? a : log1pf(expf(a));       // softplus(alpha)
    float z = sp * (kappa[e] - c);
    float sig = 1.f / (1.f + expf(-z));
    float wp = wval[e] * (EPS_C + (1.f - EPS_C) * sig);
    w_prime[e] = wp;
    int r = rows[e];
    atomicAdd(&deg[r], wp);
    atomicAdd(&count[r], 1);
}

__global__ __launch_bounds__(256) void dinv_kernel(float* __restrict__ deg, int N)
{
    int i = blockIdx.x * 256 + threadIdx.x;
    if (i >= N) return;
    deg[i] = 1.f / (sqrtf(deg[i]) + 1e-8f);
}

// exclusive scan of count -> row_start.  1024 elements per block.
__global__ __launch_bounds__(256) void scan_a_kernel(
    const int* __restrict__ cnt, int* __restrict__ rs, int* __restrict__ bsum, int N)
{
    __shared__ int lds[256];
    int tid = threadIdx.x;
    int idx = blockIdx.x * 1024 + tid * 4;
    int v0 = 0, v1 = 0, v2 = 0, v3 = 0;
    if (idx + 3 < N) {
        int4 cv = *(const int4*)(cnt + idx);
        v0 = cv.x; v1 = cv.y; v2 = cv.z; v3 = cv.w;
    } else {
        if (idx     < N) v0 = cnt[idx];
        if (idx + 1 < N) v1 = cnt[idx + 1];
        if (idx + 2 < N) v2 = cnt[idx + 2];
        if (idx + 3 < N) v3 = cnt[idx + 3];
    }
    int tsum = v0 + v1 + v2 + v3;
    lds[tid] = tsum;
    __syncthreads();
    for (int off = 1; off < 256; off <<= 1) {
        int x = lds[tid];
        int y = (tid >= off) ? lds[tid - off] : 0;
        __syncthreads();
        lds[tid] = x + y;
        __syncthreads();
    }
    int tprefix = lds[tid] - tsum;   // exclusive prefix of this thread's chunk
    if (tid == 255) bsum[blockIdx.x] = lds[255];
    int p = tprefix;
    if (idx     < N) rs[idx]     = p;  p += v0;
    if (idx + 1 < N) rs[idx + 1] = p;  p += v1;
    if (idx + 2 < N) rs[idx + 2] = p;  p += v2;
    if (idx + 3 < N) rs[idx + 3] = p;
}

__global__ void scan_b_kernel(int* __restrict__ bsum, int nb)
{
    if (threadIdx.x == 0 && blockIdx.x == 0) {
        int run = 0;
        for (int i = 0; i < nb; i++) { int t = bsum[i]; bsum[i] = run; run += t; }
    }
}

__global__ __launch_bounds__(256) void scan_c_kernel(
    int* __restrict__ rs, int* __restrict__ cursor, const int* __restrict__ bsum, int N)
{
    int i = blockIdx.x * 256 + threadIdx.x;
    if (i >= N) return;
    int v = rs[i] + bsum[i >> 10];
    rs[i] = v;
    cursor[i] = v;
}

__global__ __launch_bounds__(256) void scatter_kernel(
    const int* __restrict__ rows, const int* __restrict__ cols,
    const float* __restrict__ w_prime, const float* __restrict__ dinv,
    int* __restrict__ cursor, int2* __restrict__ edges, int E)
{
    int e = blockIdx.x * 256 + threadIdx.x;
    if (e >= E) return;
    int r = rows[e], c = cols[e];
    float wn = dinv[r] * w_prime[e] * dinv[c];
    int pos = atomicAdd(&cursor[r], 1);
    edges[pos] = make_int2(c, __float_as_int(wn));
}

// ---------------- Chebyshev SpMM (fused recurrence + accumulate) ----------------
// one wave (64 lanes) per row; lane handles 2 features (float2).
// first==1:  Tnew = -sum            ; acc  = c0*X + ck*Tnew
// first==0:  Tnew = -2*sum - Tprev  ; acc += ck*Tnew     (Tnew may alias Tprev)
__global__ __launch_bounds__(256) void cheb_spmm_kernel(
    const int2* __restrict__ edges, const int* __restrict__ rs,
    const int* __restrict__ cnt,
    const float* __restrict__ Tcur, const float* __restrict__ Tprev,
    float* __restrict__ Tnew, float* __restrict__ acc,
    const float* __restrict__ X, float c0, float ck, int first, int N)
{
    int gw = (blockIdx.x * blockDim.x + threadIdx.x) >> 6;
    if (gw >= N) return;
    int lane = threadIdx.x & 63;
    int s = rs[gw];
    int e = s + cnt[gw];
    float sx = 0.f, sy = 0.f;
    for (int i = s; i < e; i++) {
        int2 ed = edges[i];
        float w = __int_as_float(ed.y);
        float2 y = *(const float2*)(Tcur + (size_t)ed.x * DFEAT + lane * 2);
        sx = fmaf(w, y.x, sx);
        sy = fmaf(w, y.y, sy);
    }
    size_t off = (size_t)gw * DFEAT + lane * 2;
    if (first) {
        float tnx = -sx, tny = -sy;
        *(float2*)(Tnew + off) = make_float2(tnx, tny);
        float2 xv = *(const float2*)(X + off);
        *(float2*)(acc + off) = make_float2(fmaf(ck, tnx, c0 * xv.x),
                                            fmaf(ck, tny, c0 * xv.y));
    } else {
        float2 tp = *(const float2*)(Tprev + off);
        float tnx = fmaf(-2.f, sx, -tp.x);
        float tny = fmaf(-2.f, sy, -tp.y);
        *(float2*)(Tnew + off) = make_float2(tnx, tny);
        float2 av = *(const float2*)(acc + off);
        *(float2*)(acc + off) = make_float2(fmaf(ck, tnx, av.x),
                                            fmaf(ck, tny, av.y));
    }
}

// ---------------- host ----------------

static void cheb_coeffs_host(float* cf)
{
    const int m = 30;
    const double t_scale = 5.0, lambda_max = 2.0;
    double xv[30], fv[30], th[30];
    for (int j = 0; j < m; j++) {
        th[j] = M_PI * (j + 0.5) / m;
        xv[j] = cos(th[j]);
        double lam = lambda_max / 2.0 * (xv[j] + 1.0);
        fv[j] = exp(-t_scale * lam);
    }
    for (int k = 0; k < m; k++) {
        double s = 0.0;
        for (int j = 0; j < m; j++) s += fv[j] * cos((double)k * th[j]);
        double v = 2.0 / m * s;
        if (k == 0) v *= 0.5;
        cf[k] = (float)v;
    }
}

extern "C" void kernel_launch(void* const* d_in, const int* in_sizes, int n_in,
                              void* d_out, int out_size, void* d_ws, size_t ws_size,
                              hipStream_t stream)
{
    const int*   Widx   = (const int*)d_in[0];
    const float* Wval   = (const float*)d_in[1];
    const float* kappa  = (const float*)d_in[2];
    const float* X      = (const float*)d_in[3];
    const float* alpha  = (const float*)d_in[4];
    const float* center = (const float*)d_in[5];

    int E = in_sizes[1];
    int N = in_sizes[3] / DFEAT;
    const int* rows = Widx;
    const int* cols = Widx + E;
    float* out = (float*)d_out;

    // workspace layout (256B aligned chunks)
    char* p = (char*)d_ws;
    auto alloc = [&](size_t bytes) -> void* {
        void* r = (void*)p;
        p += (bytes + 255) & ~((size_t)255);
        return r;
    };
    float* bufA    = (float*)alloc((size_t)N * DFEAT * 4);
    float* bufB    = (float*)alloc((size_t)N * DFEAT * 4);
    float* w_prime = (float*)alloc((size_t)E * 4);
    float* deg     = (float*)alloc((size_t)N * 4);   // becomes d_inv_sqrt in place
    int*   count   = (int*)alloc((size_t)N * 4);
    int*   rs      = (int*)alloc((size_t)N * 4);
    int*   cursor  = (int*)alloc((size_t)N * 4);
    int*   bsum    = (int*)alloc(4096);
    int2*  edges   = (int2*)alloc((size_t)E * 8);

    hipMemsetAsync(deg, 0, (size_t)N * 4, stream);
    hipMemsetAsync(count, 0, (size_t)N * 4, stream);

    float cf[30];
    cheb_coeffs_host(cf);

    int ge = (E + 255) / 256;
    int gn = (N + 255) / 256;

    edge_prep_kernel<<<ge, 256, 0, stream>>>(rows, Wval, kappa, alpha, center,
                                             w_prime, deg, count, E);
    dinv_kernel<<<gn, 256, 0, stream>>>(deg, N);

    int nb = (N + 1023) / 1024;
    scan_a_kernel<<<nb, 256, 0, stream>>>(count, rs, bsum, N);
    scan_b_kernel<<<1, 64, 0, stream>>>(bsum, nb);
    scan_c_kernel<<<gn, 256, 0, stream>>>(rs, cursor, bsum, N);

    scatter_kernel<<<ge, 256, 0, stream>>>(rows, cols, w_prime, deg, cursor, edges, E);

    int spmm_blocks = ((size_t)N * 64 + 255) / 256;

    // T1 = L X ; acc = c0*X + c1*T1
    cheb_spmm_kernel<<<spmm_blocks, 256, 0, stream>>>(
        edges, rs, count, X, X, bufA, out, X, cf[0], cf[1], 1, N);

    const float* Tprev = X;
    const float* Tcur  = bufA;
    float*       Tnew  = bufB;
    for (int k = 2; k < 30; k++) {
        cheb_spmm_kernel<<<spmm_blocks, 256, 0, stream>>>(
            edges, rs, count, Tcur, Tprev, Tnew, out, X, 0.f, cf[k], 0, N);
        const float* newPrev = Tcur;
        const float* newCur  = Tnew;
        Tnew  = (float*)Tcur;   // overwrite the retiring T_{k-1} buffer in place
        Tprev = newPrev;
        Tcur  = newCur;
    }
}

// Round 2
// 4172.085 us; speedup vs baseline: 1.2978x; 1.2978x over previous
//
#include <hip/hip_runtime.h>
#include <math.h>

#define DFEAT 128
#define EPS_C 0.01f

// ---------------- edge preprocessing ----------------

__global__ __launch_bounds__(256) void edge_prep_kernel(
    const int* __restrict__ rows, const float* __restrict__ wval,
    const float* __restrict__ kappa, const float* __restrict__ alpha_p,
    const float* __restrict__ center_p, float* __restrict__ w_prime,
    float* __restrict__ deg, int* __restrict__ count, int E)
{
    int e = blockIdx.x * 256 + threadIdx.x;
    if (e >= E) return;
    float a = alpha_p[0];
    float c = center_p[0];
    float sp = (a > 20.f) ? a : log1pf(expf(a));       // softplus(alpha)
    float z = sp * (kappa[e] - c);
    float sig = 1.f / (1.f + expf(-z));
    float wp = wval[e] * (EPS_C + (1.f - EPS_C) * sig);
    w_prime[e] = wp;
    int r = rows[e];
    atomicAdd(&deg[r], wp);
    atomicAdd(&count[r], 1);
}

__global__ __launch_bounds__(256) void dinv_kernel(float* __restrict__ deg, int N)
{
    int i = blockIdx.x * 256 + threadIdx.x;
    if (i >= N) return;
    deg[i] = 1.f / (sqrtf(deg[i]) + 1e-8f);
}

// exclusive scan of count -> row_start.  1024 elements per block.
__global__ __launch_bounds__(256) void scan_a_kernel(
    const int* __restrict__ cnt, int* __restrict__ rs, int* __restrict__ bsum, int N)
{
    __shared__ int lds[256];
    int tid = threadIdx.x;
    int idx = blockIdx.x * 1024 + tid * 4;
    int v0 = 0, v1 = 0, v2 = 0, v3 = 0;
    if (idx + 3 < N) {
        int4 cv = *(const int4*)(cnt + idx);
        v0 = cv.x; v1 = cv.y; v2 = cv.z; v3 = cv.w;
    } else {
        if (idx     < N) v0 = cnt[idx];
        if (idx + 1 < N) v1 = cnt[idx + 1];
        if (idx + 2 < N) v2 = cnt[idx + 2];
        if (idx + 3 < N) v3 = cnt[idx + 3];
    }
    int tsum = v0 + v1 + v2 + v3;
    lds[tid] = tsum;
    __syncthreads();
    for (int off = 1; off < 256; off <<= 1) {
        int x = lds[tid];
        int y = (tid >= off) ? lds[tid - off] : 0;
        __syncthreads();
        lds[tid] = x + y;
        __syncthreads();
    }
    int tprefix = lds[tid] - tsum;   // exclusive prefix of this thread's chunk
    if (tid == 255) bsum[blockIdx.x] = lds[255];
    int p = tprefix;
    if (idx     < N) rs[idx]     = p;  p += v0;
    if (idx + 1 < N) rs[idx + 1] = p;  p += v1;
    if (idx + 2 < N) rs[idx + 2] = p;  p += v2;
    if (idx + 3 < N) rs[idx + 3] = p;
}

__global__ void scan_b_kernel(int* __restrict__ bsum, int nb)
{
    if (threadIdx.x == 0 && blockIdx.x == 0) {
        int run = 0;
        for (int i = 0; i < nb; i++) { int t = bsum[i]; bsum[i] = run; run += t; }
    }
}

__global__ __launch_bounds__(256) void scan_c_kernel(
    int* __restrict__ rs, int* __restrict__ cursor, const int* __restrict__ bsum, int N)
{
    int i = blockIdx.x * 256 + threadIdx.x;
    if (i >= N) return;
    int v = rs[i] + bsum[i >> 10];
    rs[i] = v;
    cursor[i] = v;
}

__global__ __launch_bounds__(256) void scatter_kernel(
    const int* __restrict__ rows, const int* __restrict__ cols,
    const float* __restrict__ w_prime, const float* __restrict__ dinv,
    int* __restrict__ cursor, int2* __restrict__ edges, int E)
{
    int e = blockIdx.x * 256 + threadIdx.x;
    if (e >= E) return;
    int r = rows[e], c = cols[e];
    float wn = dinv[r] * w_prime[e] * dinv[c];
    int pos = atomicAdd(&cursor[r], 1);
    edges[pos] = make_int2(c, __float_as_int(wn));
}

// ---------------- Chebyshev SpMM (fused recurrence + accumulate) ----------------
// One wave per row. Half-wave (32 lanes) per edge, float4 per lane (full 512B
// row per half-wave per gather). Unroll x2 -> 4 independent gathers in flight.
__global__ __launch_bounds__(256) void cheb_spmm_kernel(
    const int2* __restrict__ edges, const int* __restrict__ rs,
    const int* __restrict__ cnt,
    const float* __restrict__ Tcur, const float* __restrict__ Tprev,
    float* __restrict__ Tnew, float* __restrict__ acc,
    const float* __restrict__ X, float c0, float ck, int first, int N)
{
    int gw = (blockIdx.x * blockDim.x + threadIdx.x) >> 6;
    if (gw >= N) return;
    int lane = threadIdx.x & 63;
    int half = lane >> 5;          // which edge of a pair
    int fl   = lane & 31;          // feature lane: floats fl*4 .. fl*4+3
    int s = rs[gw];
    int e = s + cnt[gw];

    float4 a0 = make_float4(0.f, 0.f, 0.f, 0.f);
    float4 a1 = make_float4(0.f, 0.f, 0.f, 0.f);

    int i = s + half;
    // unrolled: edges i and i+2 for this half (4 edges/wave in flight)
    for (; i + 2 < e; i += 4) {
        int2 e0 = edges[i];
        int2 e1 = edges[i + 2];
        const float4 v0 = *(const float4*)(Tcur + (size_t)e0.x * DFEAT + fl * 4);
        const float4 v1 = *(const float4*)(Tcur + (size_t)e1.x * DFEAT + fl * 4);
        float w0 = __int_as_float(e0.y);
        float w1 = __int_as_float(e1.y);
        a0.x = fmaf(w0, v0.x, a0.x);
        a0.y = fmaf(w0, v0.y, a0.y);
        a0.z = fmaf(w0, v0.z, a0.z);
        a0.w = fmaf(w0, v0.w, a0.w);
        a1.x = fmaf(w1, v1.x, a1.x);
        a1.y = fmaf(w1, v1.y, a1.y);
        a1.z = fmaf(w1, v1.z, a1.z);
        a1.w = fmaf(w1, v1.w, a1.w);
    }
    for (; i < e; i += 2) {
        int2 e0 = edges[i];
        const float4 v0 = *(const float4*)(Tcur + (size_t)e0.x * DFEAT + fl * 4);
        float w0 = __int_as_float(e0.y);
        a0.x = fmaf(w0, v0.x, a0.x);
        a0.y = fmaf(w0, v0.y, a0.y);
        a0.z = fmaf(w0, v0.z, a0.z);
        a0.w = fmaf(w0, v0.w, a0.w);
    }
    a0.x += a1.x; a0.y += a1.y; a0.z += a1.z; a0.w += a1.w;

    // cross-half reduction: lane l and l^32 hold partial sums for same features
    a0.x += __shfl_xor(a0.x, 32);
    a0.y += __shfl_xor(a0.y, 32);
    a0.z += __shfl_xor(a0.z, 32);
    a0.w += __shfl_xor(a0.w, 32);

    size_t off = (size_t)gw * DFEAT + fl * 4;
    if (first) {
        float4 tn = make_float4(-a0.x, -a0.y, -a0.z, -a0.w);
        if (half == 0) {
            *(float4*)(Tnew + off) = tn;
        } else {
            float4 xv = *(const float4*)(X + off);
            *(float4*)(acc + off) = make_float4(fmaf(ck, tn.x, c0 * xv.x),
                                                fmaf(ck, tn.y, c0 * xv.y),
                                                fmaf(ck, tn.z, c0 * xv.z),
                                                fmaf(ck, tn.w, c0 * xv.w));
        }
    } else {
        float4 tp = *(const float4*)(Tprev + off);
        float4 tn = make_float4(fmaf(-2.f, a0.x, -tp.x),
                                fmaf(-2.f, a0.y, -tp.y),
                                fmaf(-2.f, a0.z, -tp.z),
                                fmaf(-2.f, a0.w, -tp.w));
        if (half == 0) {
            *(float4*)(Tnew + off) = tn;
        } else {
            float4 av = *(const float4*)(acc + off);
            *(float4*)(acc + off) = make_float4(fmaf(ck, tn.x, av.x),
                                                fmaf(ck, tn.y, av.y),
                                                fmaf(ck, tn.z, av.z),
                                                fmaf(ck, tn.w, av.w));
        }
    }
}

// ---------------- host ----------------

static void cheb_coeffs_host(float* cf)
{
    const int m = 30;
    const double t_scale = 5.0, lambda_max = 2.0;
    double xv[30], fv[30], th[30];
    for (int j = 0; j < m; j++) {
        th[j] = M_PI * (j + 0.5) / m;
        xv[j] = cos(th[j]);
        double lam = lambda_max / 2.0 * (xv[j] + 1.0);
        fv[j] = exp(-t_scale * lam);
    }
    for (int k = 0; k < m; k++) {
        double s = 0.0;
        for (int j = 0; j < m; j++) s += fv[j] * cos((double)k * th[j]);
        double v = 2.0 / m * s;
        if (k == 0) v *= 0.5;
        cf[k] = (float)v;
    }
}

extern "C" void kernel_launch(void* const* d_in, const int* in_sizes, int n_in,
                              void* d_out, int out_size, void* d_ws, size_t ws_size,
                              hipStream_t stream)
{
    const int*   Widx   = (const int*)d_in[0];
    const float* Wval   = (const float*)d_in[1];
    const float* kappa  = (const float*)d_in[2];
    const float* X      = (const float*)d_in[3];
    const float* alpha  = (const float*)d_in[4];
    const float* center = (const float*)d_in[5];

    int E = in_sizes[1];
    int N = in_sizes[3] / DFEAT;
    const int* rows = Widx;
    const int* cols = Widx + E;
    float* out = (float*)d_out;

    // workspace layout (256B aligned chunks)
    char* p = (char*)d_ws;
    auto alloc = [&](size_t bytes) -> void* {
        void* r = (void*)p;
        p += (bytes + 255) & ~((size_t)255);
        return r;
    };
    float* bufA    = (float*)alloc((size_t)N * DFEAT * 4);
    float* bufB    = (float*)alloc((size_t)N * DFEAT * 4);
    float* w_prime = (float*)alloc((size_t)E * 4);
    float* deg     = (float*)alloc((size_t)N * 4);   // becomes d_inv_sqrt in place
    int*   count   = (int*)alloc((size_t)N * 4);
    int*   rs      = (int*)alloc((size_t)N * 4);
    int*   cursor  = (int*)alloc((size_t)N * 4);
    int*   bsum    = (int*)alloc(4096);
    int2*  edges   = (int2*)alloc((size_t)E * 8);

    hipMemsetAsync(deg, 0, (size_t)N * 4, stream);
    hipMemsetAsync(count, 0, (size_t)N * 4, stream);

    float cf[30];
    cheb_coeffs_host(cf);

    int ge = (E + 255) / 256;
    int gn = (N + 255) / 256;

    edge_prep_kernel<<<ge, 256, 0, stream>>>(rows, Wval, kappa, alpha, center,
                                             w_prime, deg, count, E);
    dinv_kernel<<<gn, 256, 0, stream>>>(deg, N);

    int nb = (N + 1023) / 1024;
    scan_a_kernel<<<nb, 256, 0, stream>>>(count, rs, bsum, N);
    scan_b_kernel<<<1, 64, 0, stream>>>(bsum, nb);
    scan_c_kernel<<<gn, 256, 0, stream>>>(rs, cursor, bsum, N);

    scatter_kernel<<<ge, 256, 0, stream>>>(rows, cols, w_prime, deg, cursor, edges, E);

    int spmm_blocks = (int)(((size_t)N * 64 + 255) / 256);

    // T1 = L X ; acc = c0*X + c1*T1
    cheb_spmm_kernel<<<spmm_blocks, 256, 0, stream>>>(
        edges, rs, count, X, X, bufA, out, X, cf[0], cf[1], 1, N);

    const float* Tprev = X;
    const float* Tcur  = bufA;
    float*       Tnew  = bufB;
    for (int k = 2; k < 30; k++) {
        cheb_spmm_kernel<<<spmm_blocks, 256, 0, stream>>>(
            edges, rs, count, Tcur, Tprev, Tnew, out, X, 0.f, cf[k], 0, N);
        const float* newPrev = Tcur;
        const float* newCur  = Tnew;
        Tnew  = (float*)Tcur;   // overwrite the retiring T_{k-1} buffer in place
        Tprev = newPrev;
        Tcur  = newCur;
    }
}